// Round 7
// baseline (153.913 us; speedup 1.0000x reference)
//
#include <hip/hip_runtime.h>
#include <math.h>

#define B_ 4
#define L_ 2048
#define S_ 2048
#define H_ 8
#define E_ 64
#define BH_ (B_*H_)
#define EPS 1e-6f
#define LOG2E 1.44269504088896340736f

typedef __attribute__((ext_vector_type(8))) short short8;
typedef __attribute__((ext_vector_type(4))) float f32x4;

__device__ __forceinline__ unsigned short f2bf(float f) {
    unsigned int u = __float_as_uint(f);
    u = (u + 0x7fffu + ((u >> 16) & 1u)) >> 16;   // RNE
    return (unsigned short)u;
}

__device__ __forceinline__ float bf2f(unsigned short u) {
    return __uint_as_float(((unsigned int)u) << 16);
}

__device__ __forceinline__ float fast_tanh(float x) {
    float e = __expf(2.0f * x);
    return 1.0f - 2.0f / (e + 1.0f);
}

// pack 2 f32 -> 2 bf16 (RNE) in one instr
__device__ __forceinline__ unsigned int cvt_pk_bf16(float lo, float hi) {
    unsigned int r;
    asm("v_cvt_pk_bf16_f32 %0, %1, %2" : "=v"(r) : "v"(lo), "v"(hi));
    return r;
}
// 2^x directly (log2e pre-folded into the multiplier)
__device__ __forceinline__ float exp2_fast(float x) {
    float r;
    asm("v_exp_f32 %0, %1" : "=v"(r) : "v"(x));
    return r;
}
// a' = {a.q0,a.q1,b.q0,b.q1}, b' = {a.q2,a.q3,b.q2,b.q3}  (16-lane rows)
__device__ __forceinline__ void swap32(unsigned int &a, unsigned int &b) {
    asm("v_permlane32_swap_b32 %0, %1" : "+v"(a), "+v"(b));
}
// a' = {a.q0,b.q0,a.q2,b.q2}, b' = {a.q1,b.q1,a.q3,b.q3}
__device__ __forceinline__ void swap16(unsigned int &a, unsigned int &b) {
    asm("v_permlane16_swap_b32 %0, %1" : "+v"(a), "+v"(b));
}

// ---------------------------------------------------------------------------
// K0 (fused preprocessing, partitioned grid):
//  blocks [0,4096):    q/k transform (wave-per-row, 4 wide mem instrs)
//  blocks [4096,5120): v transform -> vt MFMA-frag-tiled bf16
//  blocks [5120,5152): zero-init f32 G + ksum (for gram's atomics)
// ---------------------------------------------------------------------------
__global__ __launch_bounds__(256) void pre_kernel(
    const float* __restrict__ xq, const float* __restrict__ xk,
    const float* __restrict__ xv,
    unsigned short* __restrict__ qt, unsigned short* __restrict__ kt,
    unsigned short* __restrict__ vt, float* __restrict__ Gf,
    const float* __restrict__ dwp, const float* __restrict__ dpp)
{
    __shared__ float ls[64][65];
    int bx = blockIdx.x;
    int tid = threadIdx.x;
    if (bx < 4096) {
        const float* x = (bx < 2048) ? xq : xk;
        unsigned short* xt = (bx < 2048) ? qt : kt;
        int wv = tid >> 6, ln = tid & 63;
        int bl = (bx & 2047) * 4 + wv;
        int b = bl >> 11, l = bl & 2047;
        const float* xb = x + (size_t)bl * 512;
        float4 fa = *(const float4*)(xb + ln * 4);        // h = ln>>4,   e = (ln&15)*4..+4
        float4 fb = *(const float4*)(xb + 256 + ln * 4);  // h = ln>>4+4, same e
        float s0 = fa.x + fb.x, s1 = fa.y + fb.y, s2 = fa.z + fb.z, s3 = fa.w + fb.w;
        float q0 = fa.x * fa.x + fb.x * fb.x, q1 = fa.y * fa.y + fb.y * fb.y;
        float q2 = fa.z * fa.z + fb.z * fb.z, q3 = fa.w * fa.w + fb.w * fb.w;
        // reduce over {ln^16, ln^32}: each e's 8 h-values live in that group
        s0 += __shfl_xor(s0, 16); s1 += __shfl_xor(s1, 16);
        s2 += __shfl_xor(s2, 16); s3 += __shfl_xor(s3, 16);
        q0 += __shfl_xor(q0, 16); q1 += __shfl_xor(q1, 16);
        q2 += __shfl_xor(q2, 16); q3 += __shfl_xor(q3, 16);
        s0 += __shfl_xor(s0, 32); s1 += __shfl_xor(s1, 32);
        s2 += __shfl_xor(s2, 32); s3 += __shfl_xor(s3, 32);
        q0 += __shfl_xor(q0, 32); q1 += __shfl_xor(q1, 32);
        q2 += __shfl_xor(q2, 32); q3 += __shfl_xor(q3, 32);
        float dw = dwp[0], d = dpp[0];
        auto mkw = [&](float s, float q) {
            float mean = s * 0.125f;
            float var = (q - s * mean) * (1.f / 7.f);   // ddof=1, N=8
            var = fmaxf(var, 0.f);
            return dw / (sqrtf(var) + EPS);
        };
        float w0 = mkw(s0, q0), w1 = mkw(s1, q1), w2 = mkw(s2, q2), w3 = mkw(s3, q3);
        float ta0 = fast_tanh(fa.x * w0) * d, ta1 = fast_tanh(fa.y * w1) * d;
        float ta2 = fast_tanh(fa.z * w2) * d, ta3 = fast_tanh(fa.w * w3) * d;
        float tb0 = fast_tanh(fb.x * w0) * d, tb1 = fast_tanh(fb.y * w1) * d;
        float tb2 = fast_tanh(fb.z * w2) * d, tb3 = fast_tanh(fb.w * w3) * d;
        uint2 pa, pb;
        pa.x = cvt_pk_bf16(ta0, ta1); pa.y = cvt_pk_bf16(ta2, ta3);
        pb.x = cvt_pk_bf16(tb0, tb1); pb.y = cvt_pk_bf16(tb2, tb3);
        int hh = ln >> 4, e0 = (ln & 15) * 4;
        *(uint2*)(xt + ((size_t)(b * 8 + hh) * 2048 + l) * 64 + e0) = pa;
        *(uint2*)(xt + ((size_t)(b * 8 + hh + 4) * 2048 + l) * 64 + e0) = pb;
    } else if (bx < 5120) {
        int t2 = bx - 4096;
        int s0 = (t2 & 31) * 64;
        int h = (t2 >> 5) & 7, b = t2 >> 8;
        int t = tid;
#pragma unroll
        for (int i = 0; i < 4; ++i) {
            int idx = t + i * 256;
            int r = idx >> 4, c4 = (idx & 15) * 4;
            const float4 f = *(const float4*)&xv[((size_t)(b * S_ + s0 + r) * H_ + h) * E_ + c4];
            ls[r][c4] = f.x; ls[r][c4 + 1] = f.y; ls[r][c4 + 2] = f.z; ls[r][c4 + 3] = f.w;
        }
        __syncthreads();
        size_t ob = ((size_t)(b * H_ + h) * (S_ / 64) + (s0 >> 6)) * 4096;
#pragma unroll
        for (int i = 0; i < 2; ++i) {
            int ri = t + i * 256;                  // 512 runs of 8 halfwords
            int et = ri >> 7, c = (ri >> 6) & 1, quad = (ri >> 4) & 3, m = ri & 15;
            int e = et * 16 + m, sb = c * 32 + quad * 8;
            uint4 u;
            u.x = cvt_pk_bf16(ls[sb + 0][e], ls[sb + 1][e]);
            u.y = cvt_pk_bf16(ls[sb + 2][e], ls[sb + 3][e]);
            u.z = cvt_pk_bf16(ls[sb + 4][e], ls[sb + 5][e]);
            u.w = cvt_pk_bf16(ls[sb + 6][e], ls[sb + 7][e]);
            *(uint4*)&vt[ob + (size_t)ri * 8] = u;
        }
    } else {
        // zero f32 G (32*4096) + ksum (32*64) for gram's atomic accumulate
        for (int i = (bx - 5120) * 256 + tid; i < 32 * 4096 + 32 * 64; i += 32 * 256)
            Gf[i] = 0.f;
    }
}

// ---------------------------------------------------------------------------
// K1: Gram, 4-way s-split -> 128 blocks (4 per bh, 512 s each). Partials
// combined with f32 global atomicAdd into Gf/ksum (zeroed by pre). Keeps
// the per-part in-place frag-retile of kt.
// ---------------------------------------------------------------------------
__global__ __launch_bounds__(256) void gram_kernel(
    unsigned short* __restrict__ kt, float* __restrict__ Gf,
    float* __restrict__ ksum)
{
    __shared__ unsigned short ks[128 * 72];   // pad 72: transpose-friendly
    __shared__ float gs[4096];
    int g2 = blockIdx.x;
    int bh = g2 >> 2, part = g2 & 3;
    unsigned short* base = kt + (size_t)bh * S_ * E_ + (size_t)part * 512 * E_;
    int tid = threadIdx.x, lane = tid & 63, w = tid >> 6;
    int m = lane & 15, quad = lane >> 4;

    f32x4 acc[4][4];
#pragma unroll
    for (int i = 0; i < 4; ++i)
#pragma unroll
        for (int j = 0; j < 4; ++j) acc[i][j] = (f32x4){0.f, 0.f, 0.f, 0.f};
    float ksp[4] = {0.f, 0.f, 0.f, 0.f};

    short8 stg[4];
#pragma unroll
    for (int i = 0; i < 4; ++i)
        stg[i] = *(const short8*)(base + (size_t)(tid + i * 256) * 8);

    for (int ch = 0; ch < 4; ++ch) {
        __syncthreads();                       // prior readers of ks done
#pragma unroll
        for (int i = 0; i < 4; ++i) {
            int u = tid + i * 256;
            *(short8*)&ks[(u >> 3) * 72 + (u & 7) * 8] = stg[i];
        }
        __syncthreads();
        if (ch < 3) {
#pragma unroll
            for (int i = 0; i < 4; ++i)
                stg[i] = *(const short8*)(base + (size_t)(ch + 1) * 8192 + (tid + i * 256) * 8);
        }
        // in-place frag-retile of chunk ch (2 tiles of 64 s each):
        // attn reads kf[nt][c] = 16B at tile*4096 + (nt*2+c)*512 + lane*8,
        // element j = K[s = st*64+nt*16+(lane&15)][e = c*32+(lane>>4)*8+j]
#pragma unroll
        for (int tt = 0; tt < 2; ++tt)
#pragma unroll
            for (int i = 0; i < 2; ++i) {
                int u = tid + i * 256;
                int nt = u >> 7, cc = (u >> 6) & 1, ln2 = u & 63;
                int mm = ln2 & 15, qq = ln2 >> 4;
                short8 vv = *(const short8*)&ks[(tt * 64 + nt * 16 + mm) * 72 + cc * 32 + qq * 8];
                *(uint4*)&base[(size_t)(ch * 2 + tt) * 4096 + (size_t)u * 8] = *(uint4*)&vv;
            }
        int s0 = w * 32;
        short8 af[4];
#pragma unroll
        for (int i = 0; i < 4; ++i) {
            short8 a;
#pragma unroll
            for (int kk = 0; kk < 8; ++kk) {
                unsigned short uv = ks[(s0 + quad * 8 + kk) * 72 + i * 16 + m];
                a[kk] = (short)uv;
                ksp[i] += bf2f(uv);
            }
            af[i] = a;
        }
#pragma unroll
        for (int i = 0; i < 4; ++i)
#pragma unroll
            for (int j = 0; j < 4; ++j)
                acc[i][j] = __builtin_amdgcn_mfma_f32_16x16x32_bf16(af[i], af[j], acc[i][j], 0, 0, 0);
    }
    // ksum partial: reduce over quads in-wave, then atomic (cross-wave+cross-part)
#pragma unroll
    for (int i = 0; i < 4; ++i) {
        ksp[i] += __shfl_xor(ksp[i], 16);
        ksp[i] += __shfl_xor(ksp[i], 32);
    }
    if (lane < 16) {
#pragma unroll
        for (int i = 0; i < 4; ++i)
            atomicAdd(&ksum[bh * 64 + i * 16 + lane], ksp[i]);
    }
    // G partial: 4-wave LDS reduce, then one atomicAdd per element
    for (int w2 = 0; w2 < 4; ++w2) {
        if (w == w2) {
#pragma unroll
            for (int i = 0; i < 4; ++i)
#pragma unroll
                for (int j = 0; j < 4; ++j)
#pragma unroll
                    for (int r = 0; r < 4; ++r) {
                        int idx = (i * 16 + quad * 4 + r) * 64 + j * 16 + m;
                        if (w2 == 0) gs[idx] = acc[i][j][r]; else gs[idx] += acc[i][j][r];
                    }
        }
        __syncthreads();
    }
#pragma unroll
    for (int ii = 0; ii < 16; ++ii) {
        int idx = tid + ii * 256;
        atomicAdd(&Gf[bh * 4096 + idx], gs[idx]);
    }
}

// ---------------------------------------------------------------------------
// K2: single-pass attention. ROUND-11: single-variable change vs R6 —
// main loop #pragma unroll 2 -> 4. We are GRID-limited at 8 waves/CU
// (512 blocks x 4 waves / 256 CUs), so VGPR growth up to ~250 is free;
// a 2x wider unroll window lets the compiler hoist next-tile VMEM loads
// further ahead (the ~29% non-issue stall is the target). Loop body is
// byte-identical to the measured-best R3/R6 form (R5 lesson: the compiler
// owns the schedule). Zero-LDS/zero-barrier loop, 4 waves x 32 q-rows,
// frag-tiled K/V direct from global (L2-resident), in-register P
// (cvt_pk + permlane), ones-MFMA denominator, exp2-folded alpha.
// ---------------------------------------------------------------------------
__global__ __launch_bounds__(256, 2) void attn_kernel(
    const unsigned short* __restrict__ qt,
    const unsigned short* __restrict__ ktf,   // frag-retiled by gram
    const unsigned short* __restrict__ vt,
    const float* __restrict__ Gf,
    const float* __restrict__ ksum,
    float* __restrict__ out)
{
    __shared__ float2 ascr_s[4 * 32];          // per-wave alpha scratch, 1KB
    const int tid = threadIdx.x;
    const int lane = tid & 63;
    const int w = tid >> 6;
    const int m = lane & 15;
    const int quad = lane >> 4;
    float2* ascr = ascr_s + w * 32;

    int blk = blockIdx.x;
    int bh = (blk & 7) * 4 + ((blk >> 3) & 3);   // XCD swizzle: 4 bh per XCD
    int l0 = (blk >> 5) * 128;
    int b = bh >> 3, h = bh & 7;

    const unsigned short* qtb = qt + (size_t)bh * L_ * E_;
    const unsigned short* kb  = ktf + (size_t)bh * S_ * E_;
    const unsigned short* vtb = vt + (size_t)bh * (S_ / 64) * 4096;

    // Q B-fragments: lane m <-> q-row l0 + w*32 + g*16 + m
    short8 qf[2][2];
#pragma unroll
    for (int g = 0; g < 2; ++g)
#pragma unroll
        for (int c = 0; c < 2; ++c)
            qf[g][c] = *(const short8*)(qtb + (size_t)(l0 + w * 32 + g * 16 + m) * E_ + c * 32 + quad * 8);

    // ---- in-block alpha: T = Q*G, sumsq = sum T.Q, rowsum = Q.ksum ----
    float al2[2], nalm2[2];   // log2e-folded: P = 2^(al2*score + nalm2)
    {
        const float* gb = Gf + (size_t)bh * 4096;
        short8 gfr[4][2];
#pragma unroll
        for (int j = 0; j < 4; ++j)
#pragma unroll
            for (int c = 0; c < 2; ++c) {
                const float* gp = gb + (size_t)(j * 16 + m) * 64 + c * 32 + quad * 8;
                float4 f0 = *(const float4*)gp;
                float4 f1 = *(const float4*)(gp + 4);
                uint4 u;
                u.x = cvt_pk_bf16(f0.x, f0.y); u.y = cvt_pk_bf16(f0.z, f0.w);
                u.z = cvt_pk_bf16(f1.x, f1.y); u.w = cvt_pk_bf16(f1.z, f1.w);
                gfr[j][c] = *(short8*)&u;
            }
        float ksl[4];
#pragma unroll
        for (int j = 0; j < 4; ++j) ksl[j] = ksum[bh * 64 + j * 16 + m];
#pragma unroll
        for (int g = 0; g < 2; ++g) {
            f32x4 accj[4];
#pragma unroll
            for (int j = 0; j < 4; ++j) {
                accj[j] = (f32x4){0.f, 0.f, 0.f, 0.f};
                accj[j] = __builtin_amdgcn_mfma_f32_16x16x32_bf16(qf[g][0], gfr[j][0], accj[j], 0, 0, 0);
                accj[j] = __builtin_amdgcn_mfma_f32_16x16x32_bf16(qf[g][1], gfr[j][1], accj[j], 0, 0, 0);
            }
            float ps[4] = {0, 0, 0, 0}, pr[4] = {0, 0, 0, 0};
#pragma unroll
            for (int r = 0; r < 4; ++r)
#pragma unroll
                for (int j = 0; j < 4; ++j) {
                    float qv = bf2f(qtb[(size_t)(l0 + w * 32 + g * 16 + quad * 4 + r) * E_ + j * 16 + m]);
                    ps[r] = fmaf(accj[j][r], qv, ps[r]);
                    pr[r] = fmaf(qv, ksl[j], pr[r]);
                }
#pragma unroll
            for (int mask = 1; mask < 16; mask <<= 1)
#pragma unroll
                for (int r = 0; r < 4; ++r) {
                    ps[r] += __shfl_xor(ps[r], mask);
                    pr[r] += __shfl_xor(pr[r], mask);
                }
            if (m == 0) {
#pragma unroll
                for (int r = 0; r < 4; ++r) {
                    float sum = pr[r];
                    float mu = sum * (1.f / S_);
                    float var = (ps[r] - sum * mu) * (1.f / (S_ - 1));   // ddof=1
                    var = fmaxf(var, 0.f);
                    float tau = sqrtf(var + EPS);
                    float a = 0.125f / tau;                               // scale=1/8
                    ascr[g * 16 + quad * 4 + r] = make_float2(a, a * mu);
                }
            }
        }
#pragma unroll
        for (int g = 0; g < 2; ++g) {
            float2 a2 = ascr[g * 16 + m];   // wave-private: lgkm ordering suffices
            al2[g] = a2.x * LOG2E; nalm2[g] = -a2.y * LOG2E;
        }
    }

    f32x4 oacc[2][4];
#pragma unroll
    for (int g = 0; g < 2; ++g)
#pragma unroll
        for (int et = 0; et < 4; ++et) oacc[g][et] = (f32x4){0.f, 0.f, 0.f, 0.f};
    f32x4 asum2[2];
#pragma unroll
    for (int g = 0; g < 2; ++g) asum2[g] = (f32x4){0.f, 0.f, 0.f, 0.f};

    short8 ones;
#pragma unroll
    for (int j = 0; j < 8; ++j) ones[j] = (short)0x3F80;   // bf16 1.0

#pragma unroll 4
    for (int st = 0; st < S_ / 64; ++st) {
        const unsigned short* kstb = kb + (size_t)st * 4096;
        const unsigned short* vstb = vtb + (size_t)st * 4096;
        // K A-frags: contiguous 1KB wave-loads from frag-retiled kt
        short8 kf[4][2];
#pragma unroll
        for (int nt = 0; nt < 4; ++nt)
#pragma unroll
            for (int c = 0; c < 2; ++c)
                kf[nt][c] = *(const short8*)(kstb + (nt * 2 + c) * 512 + lane * 8);
        // V B-frags: contiguous 1KB wave-loads from frag-tiled vt
        short8 vf[2][4];
#pragma unroll
        for (int c = 0; c < 2; ++c)
#pragma unroll
            for (int et = 0; et < 4; ++et)
                vf[c][et] = *(const short8*)(vstb + et * 1024 + c * 512 + lane * 8);

        // QK + softmax, packed in-register: W[g][nt][u] = bf16pair(p[2u],p[2u+1])
        unsigned int W[2][4][2];
#pragma unroll
        for (int nt = 0; nt < 4; ++nt)
#pragma unroll
            for (int g = 0; g < 2; ++g) {
                f32x4 acc = (f32x4){0.f, 0.f, 0.f, 0.f};
                acc = __builtin_amdgcn_mfma_f32_16x16x32_bf16(kf[nt][0], qf[g][0], acc, 0, 0, 0);
                acc = __builtin_amdgcn_mfma_f32_16x16x32_bf16(kf[nt][1], qf[g][1], acc, 0, 0, 0);
                float p0 = exp2_fast(fmaf(al2[g], acc[0], nalm2[g]));
                float p1 = exp2_fast(fmaf(al2[g], acc[1], nalm2[g]));
                float p2 = exp2_fast(fmaf(al2[g], acc[2], nalm2[g]));
                float p3 = exp2_fast(fmaf(al2[g], acc[3], nalm2[g]));
                W[g][nt][0] = cvt_pk_bf16(p0, p1);
                W[g][nt][1] = cvt_pk_bf16(p2, p3);
            }
        // in-register P redistribution -> PV A-frags + PV + denominator
#pragma unroll
        for (int g = 0; g < 2; ++g) {
            short8 pf[2];
#pragma unroll
            for (int c = 0; c < 2; ++c) {
                unsigned int a0 = W[g][2 * c][0], b0 = W[g][2 * c + 1][0];
                unsigned int a1 = W[g][2 * c][1], b1 = W[g][2 * c + 1][1];
                swap32(a0, b0); swap16(a0, b0);
                swap32(a1, b1); swap16(a1, b1);
                uint4 pk4;
                pk4.x = a0; pk4.y = a1; pk4.z = b0; pk4.w = b1;
                pf[c] = *(short8*)&pk4;
            }
#pragma unroll
            for (int et = 0; et < 4; ++et) {
                oacc[g][et] = __builtin_amdgcn_mfma_f32_16x16x32_bf16(pf[0], vf[0][et], oacc[g][et], 0, 0, 0);
                oacc[g][et] = __builtin_amdgcn_mfma_f32_16x16x32_bf16(pf[1], vf[1][et], oacc[g][et], 0, 0, 0);
            }
            asum2[g] = __builtin_amdgcn_mfma_f32_16x16x32_bf16(pf[0], ones, asum2[g], 0, 0, 0);
            asum2[g] = __builtin_amdgcn_mfma_f32_16x16x32_bf16(pf[1], ones, asum2[g], 0, 0, 0);
        }
    }

    // store: asum2[g][r] is the full denominator for q-row g*16+quad*4+r
#pragma unroll
    for (int g = 0; g < 2; ++g)
#pragma unroll
        for (int r = 0; r < 4; ++r) {
            float rd = 1.0f / asum2[g][r];
            size_t row = (size_t)(b * L_ + l0 + w * 32 + g * 16 + quad * 4 + r);
#pragma unroll
            for (int et = 0; et < 4; ++et)
                out[(row * H_ + h) * E_ + et * 16 + m] = oacc[g][et][r] * rd;
        }
}

extern "C" void kernel_launch(void* const* d_in, const int* in_sizes, int n_in,
                              void* d_out, int out_size, void* d_ws, size_t ws_size,
                              hipStream_t stream)
{
    const float* q = (const float*)d_in[0];
    const float* k = (const float*)d_in[1];
    const float* v = (const float*)d_in[2];
    // d_in[3] = attn_mask (unused)
    const float* dw = (const float*)d_in[4];
    const float* dp = (const float*)d_in[5];
    float* out = (float*)d_out;

    unsigned short* qt = (unsigned short*)d_ws;              // [B,H,L,E] bf16, 8MB
    unsigned short* kt = qt + (size_t)BH_ * L_ * E_;         // [B,H,S,E] bf16 -> frag-retiled by gram
    unsigned short* vt = kt + (size_t)BH_ * S_ * E_;         // frag-tiled, 8MB
    float* Gf = (float*)(vt + (size_t)BH_ * E_ * S_);        // [B,H,64,64] f32 (atomic-accumulated)
    float* ksum = Gf + (size_t)BH_ * 4096;                   // [B,H,64] f32 (contiguous after Gf)

    pre_kernel<<<5152, 256, 0, stream>>>(q, k, v, qt, kt, vt, Gf, dw, dp);
    gram_kernel<<<128, 256, 0, stream>>>(kt, Gf, ksum);
    attn_kernel<<<512, 256, 0, stream>>>(qt, kt, vt, Gf, ksum, out);
}